// Round 1
// baseline (1090.133 us; speedup 1.0000x reference)
//
#include <hip/hip_runtime.h>

#define NB 4
#define NP 900
#define ND 512
#define NH 8
#define NDK 64
#define NROWS (NB*NP)          // 3600
#define SSZ (NP*NP)            // 810000
#define NBH (NB*NH)            // 32
#define SIDE 30

// ---------------- projection: O[b,h,p,c] = sum_k X[b,p,k] * W[h*64+c,k] + bias[h*64+c] ----------
__global__ __launch_bounds__(256) void proj_kernel(
    const float* __restrict__ query, const float* __restrict__ key_t,
    const float* __restrict__ Wq, const float* __restrict__ bq,
    const float* __restrict__ Wk, const float* __restrict__ bk,
    float* __restrict__ Qo, float* __restrict__ Ko)
{
    const float *X, *W, *bias;
    float* O;
    if (blockIdx.z == 0) { X = query; W = Wq; bias = bq; O = Qo; }
    else                 { X = key_t; W = Wk; bias = bk; O = Ko; }

    __shared__ __align__(16) float As[16][68];   // [k][i], padded
    __shared__ __align__(16) float Bs[16][68];   // [k][j]

    const int i0 = blockIdx.x * 64;
    const int h  = blockIdx.y;                   // j0 = 64*h, head index
    const int j0 = h * 64;
    const int tid = threadIdx.x;
    const int tx = tid & 15, ty = tid >> 4;

    float acc[4][4] = {};

    for (int k0 = 0; k0 < ND; k0 += 16) {
        const int r  = tid >> 2;                 // 0..63
        const int kk = (tid & 3) * 4;            // 0,4,8,12
        float4 av = make_float4(0.f, 0.f, 0.f, 0.f);
        const int gi = i0 + r;
        if (gi < NROWS) av = *(const float4*)(X + (size_t)gi * ND + k0 + kk);
        As[kk+0][r] = av.x; As[kk+1][r] = av.y; As[kk+2][r] = av.z; As[kk+3][r] = av.w;
        const float4 bv = *(const float4*)(W + (size_t)(j0 + r) * ND + k0 + kk);
        Bs[kk+0][r] = bv.x; Bs[kk+1][r] = bv.y; Bs[kk+2][r] = bv.z; Bs[kk+3][r] = bv.w;
        __syncthreads();
        #pragma unroll
        for (int k = 0; k < 16; ++k) {
            const float4 a4 = *(const float4*)&As[k][ty*4];
            const float4 b4 = *(const float4*)&Bs[k][tx*4];
            const float aa[4] = {a4.x, a4.y, a4.z, a4.w};
            const float bb[4] = {b4.x, b4.y, b4.z, b4.w};
            #pragma unroll
            for (int ii = 0; ii < 4; ++ii)
                #pragma unroll
                for (int jj = 0; jj < 4; ++jj)
                    acc[ii][jj] = fmaf(aa[ii], bb[jj], acc[ii][jj]);
        }
        __syncthreads();
    }

    #pragma unroll
    for (int ii = 0; ii < 4; ++ii) {
        const int gi = i0 + ty*4 + ii;
        if (gi >= NROWS) continue;
        const int b = gi / NP, p = gi - b * NP;
        float4 o;
        o.x = acc[ii][0] + bias[j0 + tx*4 + 0];
        o.y = acc[ii][1] + bias[j0 + tx*4 + 1];
        o.z = acc[ii][2] + bias[j0 + tx*4 + 2];
        o.w = acc[ii][3] + bias[j0 + tx*4 + 3];
        *(float4*)(O + ((size_t)(b*NH + h)*NP + p)*NDK + tx*4) = o;
    }
}

// ---------------- scores: S[bh,p,q] = sum_c Q[bh,p,c]*K[bh,q,c] ----------------
__global__ __launch_bounds__(256) void scores_kernel(
    const float* __restrict__ Q, const float* __restrict__ K, float* __restrict__ S)
{
    __shared__ __align__(16) float Qs[64][68];   // [k][p]
    __shared__ __align__(16) float Ks[64][68];   // [k][q]

    const int bh = blockIdx.z;
    const int q0 = blockIdx.x * 64;
    const int p0 = blockIdx.y * 64;
    const float* Qb = Q + (size_t)bh * NP * NDK;
    const float* Kb = K + (size_t)bh * NP * NDK;
    const int tid = threadIdx.x;
    const int tx = tid & 15, ty = tid >> 4;
    const int r = tid >> 2, l = tid & 3;

    #pragma unroll
    for (int u = 0; u < 4; ++u) {
        const int k = (l + 4*u) * 4;
        float4 qv = make_float4(0.f,0.f,0.f,0.f), kv = make_float4(0.f,0.f,0.f,0.f);
        if (p0 + r < NP) qv = *(const float4*)(Qb + (size_t)(p0 + r) * NDK + k);
        if (q0 + r < NP) kv = *(const float4*)(Kb + (size_t)(q0 + r) * NDK + k);
        Qs[k+0][r]=qv.x; Qs[k+1][r]=qv.y; Qs[k+2][r]=qv.z; Qs[k+3][r]=qv.w;
        Ks[k+0][r]=kv.x; Ks[k+1][r]=kv.y; Ks[k+2][r]=kv.z; Ks[k+3][r]=kv.w;
    }
    __syncthreads();

    float acc[4][4] = {};
    #pragma unroll 8
    for (int k = 0; k < NDK; ++k) {
        const float4 a4 = *(const float4*)&Qs[k][ty*4];
        const float4 b4 = *(const float4*)&Ks[k][tx*4];
        const float aa[4] = {a4.x, a4.y, a4.z, a4.w};
        const float bb[4] = {b4.x, b4.y, b4.z, b4.w};
        #pragma unroll
        for (int ii = 0; ii < 4; ++ii)
            #pragma unroll
            for (int jj = 0; jj < 4; ++jj)
                acc[ii][jj] = fmaf(aa[ii], bb[jj], acc[ii][jj]);
    }

    #pragma unroll
    for (int ii = 0; ii < 4; ++ii) {
        const int gp = p0 + ty*4 + ii;
        const int gq = q0 + tx*4;
        if (gp < NP && gq < NP) {   // 900 % 4 == 0 so float4 is all-or-nothing
            float4 o;
            o.x = acc[ii][0]; o.y = acc[ii][1]; o.z = acc[ii][2]; o.w = acc[ii][3];
            *(float4*)(S + (size_t)bh*SSZ + (size_t)gp*NP + gq) = o;
        }
    }
}

// ---------------- column argmax over p (first-index tie-break), split into 4 p-chunks ----------
__global__ __launch_bounds__(256) void argmax_part_kernel(
    const float* __restrict__ S, float* __restrict__ pmax, int* __restrict__ pidx)
{
    const int bh = blockIdx.y;
    const int q = blockIdx.x * 256 + threadIdx.x;
    const int c = blockIdx.z;
    if (q >= NP) return;
    const float* col = S + (size_t)bh * SSZ + q;
    const int p0 = c * 225, p1 = p0 + 225;
    float best = -3.4e38f;
    int bi = p0;
    #pragma unroll 5
    for (int p = p0; p < p1; ++p) {
        const float v = col[(size_t)p * NP];
        if (v > best) { best = v; bi = p; }   // strict > keeps first index
    }
    pmax[((size_t)c*NBH + bh)*NP + q] = best;
    pidx[((size_t)c*NBH + bh)*NP + q] = bi;
}

__global__ __launch_bounds__(256) void argmax_combine_kernel(
    const float* __restrict__ pmax, const int* __restrict__ pidx, int* __restrict__ idxo)
{
    const int t = blockIdx.x * 256 + threadIdx.x;
    if (t >= NBH * NP) return;
    const int bh = t / NP, q = t - bh * NP;
    float best = -3.4e38f; int bi = 0;
    #pragma unroll
    for (int cc = 0; cc < 4; ++cc) {          // ascending chunk order preserves first-index
        const float v = pmax[((size_t)cc*NBH + bh)*NP + q];
        const int  i = pidx[((size_t)cc*NBH + bh)*NP + q];
        if (v > best) { best = v; bi = i; }
    }
    idxo[t] = bi;
}

// ---------------- gaussian modulate + scale + softmax, in-place on S ----------------
__global__ __launch_bounds__(256) void modulate_softmax_kernel(
    float* __restrict__ S, const int* __restrict__ idx)
{
    __shared__ float vals[NP];
    __shared__ int sidx[NP];
    __shared__ float red[4];

    const int p = blockIdx.x;
    const int bh = blockIdx.y;
    const int tid = threadIdx.x;
    float* row = S + (size_t)bh * SSZ + (size_t)p * NP;

    // row coords on linspace(-1,1,30); argmax coords stay raw ints (reference quirk)
    const float ax = -1.f + (2.f/29.f) * (float)(p % SIDE);
    const float ay = -1.f + (2.f/29.f) * (float)(p / SIDE);

    for (int q = tid; q < NP; q += 256) sidx[q] = idx[bh*NP + q];
    __syncthreads();

    float lmax = -3.4e38f;
    for (int q = tid; q < NP; q += 256) {
        const int id = sidx[q];
        const float ix = (float)(id % SIDE);
        const float iy = (float)(id / SIDE);
        const float dx = ax - ix, dy = ay - iy;
        const float g = __expf(-(dx*dx + dy*dy) * 0.02f);   // 1/(2*sigma^2), sigma=5
        const float v = row[q] * g * 0.125f;                 // /sqrt(dk)
        vals[q] = v;
        lmax = fmaxf(lmax, v);
    }
    #pragma unroll
    for (int off = 32; off > 0; off >>= 1)
        lmax = fmaxf(lmax, __shfl_down(lmax, off, 64));
    if ((tid & 63) == 0) red[tid >> 6] = lmax;
    __syncthreads();
    const float rmax = fmaxf(fmaxf(red[0], red[1]), fmaxf(red[2], red[3]));

    float lsum = 0.f;
    for (int q = tid; q < NP; q += 256) {
        const float e = __expf(vals[q] - rmax);
        vals[q] = e;
        lsum += e;
    }
    #pragma unroll
    for (int off = 32; off > 0; off >>= 1)
        lsum += __shfl_down(lsum, off, 64);
    __syncthreads();
    if ((tid & 63) == 0) red[tid >> 6] = lsum;
    __syncthreads();
    const float rsum = red[0] + red[1] + red[2] + red[3];
    const float inv = 1.f / rsum;
    for (int q = tid; q < NP; q += 256) row[q] = vals[q] * inv;
}

// ---------------- fused conv1(8->32,relu) + conv2(32->8,relu) + value-weighted reduce ----------
// 16x16 output tile per block; conv1 halo tile (18x18) in LDS in two 16-oc phases.
__global__ __launch_bounds__(256) void conv_fused_kernel(
    const float* __restrict__ attn, const float* __restrict__ w1, const float* __restrict__ b1,
    const float* __restrict__ w2, const float* __restrict__ b2,
    const float* __restrict__ value, float* __restrict__ out)
{
    __shared__ float a_s[8][20][20];      // attn tile, offset -2
    __shared__ float c1_s[16][18][18];    // conv1 oc-chunk, offset -1

    const int b = blockIdx.z;
    const int gx0 = blockIdx.x * 16;
    const int gy0 = blockIdx.y * 16;
    const int tid = threadIdx.x;

    for (int t = tid; t < 8*20*20; t += 256) {
        const int ic = t / 400;
        const int rem = t - ic*400;
        const int yy = rem / 20, xx = rem - (rem/20)*20;
        const int gy = gy0 - 2 + yy, gx = gx0 - 2 + xx;
        float v = 0.f;
        if (gy >= 0 && gy < NP && gx >= 0 && gx < NP)
            v = attn[(((size_t)b*NH + ic)*NP + gy)*NP + gx];
        a_s[ic][yy][xx] = v;
    }

    float acc2[8] = {};
    const int x2 = tid & 15, y2 = tid >> 4;

    #pragma unroll 1
    for (int ph = 0; ph < 2; ++ph) {
        __syncthreads();   // a_s ready (ph0) / conv2 done reading c1_s (ph1)
        #pragma unroll 1
        for (int pix = tid; pix < 18*18; pix += 256) {
            const int yy = pix / 18, xx = pix - (pix/18)*18;
            const int gy = gy0 - 1 + yy, gx = gx0 - 1 + xx;
            const bool valid = (gy >= 0 && gy < NP && gx >= 0 && gx < NP);
            float acc[16];
            #pragma unroll
            for (int o = 0; o < 16; ++o) acc[o] = b1[ph*16 + o];
            if (valid) {
                #pragma unroll
                for (int ic = 0; ic < 8; ++ic) {
                    float win[9];
                    #pragma unroll
                    for (int ky = 0; ky < 3; ++ky)
                        #pragma unroll
                        for (int kx = 0; kx < 3; ++kx)
                            win[ky*3+kx] = a_s[ic][yy+ky][xx+kx];
                    #pragma unroll
                    for (int o = 0; o < 16; ++o) {
                        const float* w = w1 + ((size_t)(ph*16 + o)*8 + ic)*9;  // uniform -> s_load
                        #pragma unroll
                        for (int t9 = 0; t9 < 9; ++t9)
                            acc[o] = fmaf(w[t9], win[t9], acc[o]);
                    }
                }
            }
            #pragma unroll
            for (int o = 0; o < 16; ++o)
                c1_s[o][yy][xx] = valid ? fmaxf(acc[o], 0.f) : 0.f;   // SAME-pad: OOB c1 = 0
        }
        __syncthreads();
        for (int icl = 0; icl < 16; ++icl) {
            float win[9];
            #pragma unroll
            for (int ky = 0; ky < 3; ++ky)
                #pragma unroll
                for (int kx = 0; kx < 3; ++kx)
                    win[ky*3+kx] = c1_s[icl][y2+ky][x2+kx];
            #pragma unroll
            for (int o = 0; o < 8; ++o) {
                const float* w = w2 + ((size_t)o*32 + ph*16 + icl)*9;   // uniform -> s_load
                #pragma unroll
                for (int t9 = 0; t9 < 9; ++t9)
                    acc2[o] = fmaf(w[t9], win[t9], acc2[o]);
            }
        }
    }

    // epilogue: out[b,p] += (1/8) * sum_h relu(conv2+b2) * value[b,q], reduced over q in tile
    const int gp = gy0 + y2, gq = gx0 + x2;
    const float val = (gp < NP && gq < NP) ? value[b*NP + gq] : 0.f;
    float s = 0.f;
    #pragma unroll
    for (int o = 0; o < 8; ++o) s += fmaxf(acc2[o] + b2[o], 0.f);
    s *= val * 0.125f;
    #pragma unroll
    for (int off = 8; off > 0; off >>= 1) s += __shfl_down(s, off, 16);
    if (x2 == 0 && gp < NP) atomicAdd(out + b*NP + gp, s);
}

extern "C" void kernel_launch(void* const* d_in, const int* in_sizes, int n_in,
                              void* d_out, int out_size, void* d_ws, size_t ws_size,
                              hipStream_t stream)
{
    const float* query = (const float*)d_in[0];
    const float* key_t = (const float*)d_in[1];
    const float* value = (const float*)d_in[2];
    const float* Wq    = (const float*)d_in[3];
    const float* bq    = (const float*)d_in[4];
    const float* Wk    = (const float*)d_in[5];
    const float* bk    = (const float*)d_in[6];
    const float* c1w   = (const float*)d_in[7];
    const float* c1b   = (const float*)d_in[8];
    const float* c2w   = (const float*)d_in[9];
    const float* c2b   = (const float*)d_in[10];
    float* out = (float*)d_out;

    float* Q    = (float*)d_ws;
    float* K    = Q + (size_t)NBH*NP*NDK;      // +1,843,200 floats
    float* S    = K + (size_t)NBH*NP*NDK;      // +1,843,200 floats (S is 25,920,000 floats)
    int*   idxb = (int*)(S + (size_t)NBH*SSZ);
    float* pmax = (float*)(idxb + NBH*NP);
    int*   pidx = (int*)(pmax + 4*NBH*NP);

    hipMemsetAsync(d_out, 0, (size_t)out_size * sizeof(float), stream);

    proj_kernel<<<dim3(57, 8, 2), 256, 0, stream>>>(query, key_t, Wq, bq, Wk, bk, Q, K);
    scores_kernel<<<dim3(15, 15, 32), 256, 0, stream>>>(Q, K, S);
    argmax_part_kernel<<<dim3(4, 32, 4), 256, 0, stream>>>(S, pmax, pidx);
    argmax_combine_kernel<<<dim3(113), 256, 0, stream>>>(pmax, pidx, idxb);
    modulate_softmax_kernel<<<dim3(900, 32), 256, 0, stream>>>(S, idxb);
    conv_fused_kernel<<<dim3(57, 57, 4), 256, 0, stream>>>(S, c1w, c1b, c2w, c2b, value, out);
}

// Round 2
// 754.837 us; speedup vs baseline: 1.4442x; 1.4442x over previous
//
#include <hip/hip_runtime.h>

#define NB 4
#define NP 900
#define ND 512
#define NH 8
#define NDK 64
#define NROWS (NB*NP)          // 3600
#define SSZ (NP*NP)            // 810000
#define NBH (NB*NH)            // 32
#define SIDE 30

// ---------------- projection: O[b,h,p,c] = sum_k X[b,p,k] * W[h*64+c,k] + bias[h*64+c] ----------
__global__ __launch_bounds__(256) void proj_kernel(
    const float* __restrict__ query, const float* __restrict__ key_t,
    const float* __restrict__ Wq, const float* __restrict__ bq,
    const float* __restrict__ Wk, const float* __restrict__ bk,
    float* __restrict__ Qo, float* __restrict__ Ko)
{
    const float *X, *W, *bias;
    float* O;
    if (blockIdx.z == 0) { X = query; W = Wq; bias = bq; O = Qo; }
    else                 { X = key_t; W = Wk; bias = bk; O = Ko; }

    __shared__ __align__(16) float As[16][68];   // [k][i], padded
    __shared__ __align__(16) float Bs[16][68];   // [k][j]

    const int i0 = blockIdx.x * 64;
    const int h  = blockIdx.y;                   // j0 = 64*h, head index
    const int j0 = h * 64;
    const int tid = threadIdx.x;
    const int tx = tid & 15, ty = tid >> 4;

    float acc[4][4] = {};

    for (int k0 = 0; k0 < ND; k0 += 16) {
        const int r  = tid >> 2;                 // 0..63
        const int kk = (tid & 3) * 4;            // 0,4,8,12
        float4 av = make_float4(0.f, 0.f, 0.f, 0.f);
        const int gi = i0 + r;
        if (gi < NROWS) av = *(const float4*)(X + (size_t)gi * ND + k0 + kk);
        As[kk+0][r] = av.x; As[kk+1][r] = av.y; As[kk+2][r] = av.z; As[kk+3][r] = av.w;
        const float4 bv = *(const float4*)(W + (size_t)(j0 + r) * ND + k0 + kk);
        Bs[kk+0][r] = bv.x; Bs[kk+1][r] = bv.y; Bs[kk+2][r] = bv.z; Bs[kk+3][r] = bv.w;
        __syncthreads();
        #pragma unroll
        for (int k = 0; k < 16; ++k) {
            const float4 a4 = *(const float4*)&As[k][ty*4];
            const float4 b4 = *(const float4*)&Bs[k][tx*4];
            const float aa[4] = {a4.x, a4.y, a4.z, a4.w};
            const float bb[4] = {b4.x, b4.y, b4.z, b4.w};
            #pragma unroll
            for (int ii = 0; ii < 4; ++ii)
                #pragma unroll
                for (int jj = 0; jj < 4; ++jj)
                    acc[ii][jj] = fmaf(aa[ii], bb[jj], acc[ii][jj]);
        }
        __syncthreads();
    }

    #pragma unroll
    for (int ii = 0; ii < 4; ++ii) {
        const int gi = i0 + ty*4 + ii;
        if (gi >= NROWS) continue;
        const int b = gi / NP, p = gi - b * NP;
        float4 o;
        o.x = acc[ii][0] + bias[j0 + tx*4 + 0];
        o.y = acc[ii][1] + bias[j0 + tx*4 + 1];
        o.z = acc[ii][2] + bias[j0 + tx*4 + 2];
        o.w = acc[ii][3] + bias[j0 + tx*4 + 3];
        *(float4*)(O + ((size_t)(b*NH + h)*NP + p)*NDK + tx*4) = o;
    }
}

// ---------------- scores: S[bh,p,q] = sum_c Q[bh,p,c]*K[bh,q,c] ----------------
__global__ __launch_bounds__(256) void scores_kernel(
    const float* __restrict__ Q, const float* __restrict__ K, float* __restrict__ S)
{
    __shared__ __align__(16) float Qs[64][68];   // [k][p]
    __shared__ __align__(16) float Ks[64][68];   // [k][q]

    const int bh = blockIdx.z;
    const int q0 = blockIdx.x * 64;
    const int p0 = blockIdx.y * 64;
    const float* Qb = Q + (size_t)bh * NP * NDK;
    const float* Kb = K + (size_t)bh * NP * NDK;
    const int tid = threadIdx.x;
    const int tx = tid & 15, ty = tid >> 4;
    const int r = tid >> 2, l = tid & 3;

    #pragma unroll
    for (int u = 0; u < 4; ++u) {
        const int k = (l + 4*u) * 4;
        float4 qv = make_float4(0.f,0.f,0.f,0.f), kv = make_float4(0.f,0.f,0.f,0.f);
        if (p0 + r < NP) qv = *(const float4*)(Qb + (size_t)(p0 + r) * NDK + k);
        if (q0 + r < NP) kv = *(const float4*)(Kb + (size_t)(q0 + r) * NDK + k);
        Qs[k+0][r]=qv.x; Qs[k+1][r]=qv.y; Qs[k+2][r]=qv.z; Qs[k+3][r]=qv.w;
        Ks[k+0][r]=kv.x; Ks[k+1][r]=kv.y; Ks[k+2][r]=kv.z; Ks[k+3][r]=kv.w;
    }
    __syncthreads();

    float acc[4][4] = {};
    #pragma unroll 8
    for (int k = 0; k < NDK; ++k) {
        const float4 a4 = *(const float4*)&Qs[k][ty*4];
        const float4 b4 = *(const float4*)&Ks[k][tx*4];
        const float aa[4] = {a4.x, a4.y, a4.z, a4.w};
        const float bb[4] = {b4.x, b4.y, b4.z, b4.w};
        #pragma unroll
        for (int ii = 0; ii < 4; ++ii)
            #pragma unroll
            for (int jj = 0; jj < 4; ++jj)
                acc[ii][jj] = fmaf(aa[ii], bb[jj], acc[ii][jj]);
    }

    #pragma unroll
    for (int ii = 0; ii < 4; ++ii) {
        const int gp = p0 + ty*4 + ii;
        const int gq = q0 + tx*4;
        if (gp < NP && gq < NP) {   // 900 % 4 == 0 so float4 is all-or-nothing
            float4 o;
            o.x = acc[ii][0]; o.y = acc[ii][1]; o.z = acc[ii][2]; o.w = acc[ii][3];
            *(float4*)(S + (size_t)bh*SSZ + (size_t)gp*NP + gq) = o;
        }
    }
}

// ---------------- column argmax over p (first-index tie-break), split into 4 p-chunks ----------
__global__ __launch_bounds__(256) void argmax_part_kernel(
    const float* __restrict__ S, float* __restrict__ pmax, int* __restrict__ pidx)
{
    const int bh = blockIdx.y;
    const int q = blockIdx.x * 256 + threadIdx.x;
    const int c = blockIdx.z;
    if (q >= NP) return;
    const float* col = S + (size_t)bh * SSZ + q;
    const int p0 = c * 225, p1 = p0 + 225;
    float best = -3.4e38f;
    int bi = p0;
    #pragma unroll 5
    for (int p = p0; p < p1; ++p) {
        const float v = col[(size_t)p * NP];
        if (v > best) { best = v; bi = p; }   // strict > keeps first index
    }
    pmax[((size_t)c*NBH + bh)*NP + q] = best;
    pidx[((size_t)c*NBH + bh)*NP + q] = bi;
}

__global__ __launch_bounds__(256) void argmax_combine_kernel(
    const float* __restrict__ pmax, const int* __restrict__ pidx, int* __restrict__ idxo)
{
    const int t = blockIdx.x * 256 + threadIdx.x;
    if (t >= NBH * NP) return;
    const int bh = t / NP, q = t - bh * NP;
    float best = -3.4e38f; int bi = 0;
    #pragma unroll
    for (int cc = 0; cc < 4; ++cc) {          // ascending chunk order preserves first-index
        const float v = pmax[((size_t)cc*NBH + bh)*NP + q];
        const int  i = pidx[((size_t)cc*NBH + bh)*NP + q];
        if (v > best) { best = v; bi = i; }
    }
    idxo[t] = bi;
}

// ---------------- gaussian modulate + scale + softmax, in-place on S ----------------
__global__ __launch_bounds__(256) void modulate_softmax_kernel(
    float* __restrict__ S, const int* __restrict__ idx)
{
    __shared__ float vals[NP];
    __shared__ int sidx[NP];
    __shared__ float red[4];

    const int p = blockIdx.x;
    const int bh = blockIdx.y;
    const int tid = threadIdx.x;
    float* row = S + (size_t)bh * SSZ + (size_t)p * NP;

    // row coords on linspace(-1,1,30); argmax coords stay raw ints (reference quirk)
    const float ax = -1.f + (2.f/29.f) * (float)(p % SIDE);
    const float ay = -1.f + (2.f/29.f) * (float)(p / SIDE);

    for (int q = tid; q < NP; q += 256) sidx[q] = idx[bh*NP + q];
    __syncthreads();

    float lmax = -3.4e38f;
    for (int q = tid; q < NP; q += 256) {
        const int id = sidx[q];
        const float ix = (float)(id % SIDE);
        const float iy = (float)(id / SIDE);
        const float dx = ax - ix, dy = ay - iy;
        const float g = __expf(-(dx*dx + dy*dy) * 0.02f);   // 1/(2*sigma^2), sigma=5
        const float v = row[q] * g * 0.125f;                 // /sqrt(dk)
        vals[q] = v;
        lmax = fmaxf(lmax, v);
    }
    #pragma unroll
    for (int off = 32; off > 0; off >>= 1)
        lmax = fmaxf(lmax, __shfl_down(lmax, off, 64));
    if ((tid & 63) == 0) red[tid >> 6] = lmax;
    __syncthreads();
    const float rmax = fmaxf(fmaxf(red[0], red[1]), fmaxf(red[2], red[3]));

    float lsum = 0.f;
    for (int q = tid; q < NP; q += 256) {
        const float e = __expf(vals[q] - rmax);
        vals[q] = e;
        lsum += e;
    }
    #pragma unroll
    for (int off = 32; off > 0; off >>= 1)
        lsum += __shfl_down(lsum, off, 64);
    __syncthreads();
    if ((tid & 63) == 0) red[tid >> 6] = lsum;
    __syncthreads();
    const float rsum = red[0] + red[1] + red[2] + red[3];
    const float inv = 1.f / rsum;
    for (int q = tid; q < NP; q += 256) row[q] = vals[q] * inv;
}

// ---------------- fused conv1(8->32,relu) + conv2(32->8,relu) + value-weighted reduce ----------
// 30x30 output tile (900 = 30 tiles x 30px exactly). conv1 tile 32x32 = 256 threads x 2x2 patch.
// 4 oc-phases of 8; weights via wave-uniform s_load; all LDS reads register-blocked (b64).
__global__ __launch_bounds__(256, 2) void conv_fused_kernel(
    const float* __restrict__ attn, const float* __restrict__ w1, const float* __restrict__ b1,
    const float* __restrict__ w2, const float* __restrict__ b2,
    const float* __restrict__ value, float* __restrict__ out)
{
    __shared__ __align__(16) float a_s[8][34][34];    // attn tile, origin (gy0-2, gx0-2)
    __shared__ __align__(16) float c1_s[8][32][34];   // conv1 oc-phase, origin (gy0-1, gx0-1)
    __shared__ float rsum[32];

    const int b   = blockIdx.z;
    const int gx0 = blockIdx.x * 30;
    const int gy0 = blockIdx.y * 30;
    const int tid = threadIdx.x;

    // ---- stage attn tile (zeros outside image) ----
    for (int t = tid; t < 8*34*34; t += 256) {
        const int ic  = t / 1156;
        const int rem = t - ic*1156;
        const int yy  = rem / 34, xx = rem - (rem/34)*34;
        const int gy = gy0 - 2 + yy, gx = gx0 - 2 + xx;
        float v = 0.f;
        if (gy >= 0 && gy < NP && gx >= 0 && gx < NP)
            v = attn[(((size_t)b*NH + ic)*NP + gy)*NP + gx];
        a_s[ic][yy][xx] = v;
    }
    if (tid < 32) rsum[tid] = 0.f;
    __syncthreads();

    // conv1 patch: 2x2 at (cy,cx) in the 32x32 c1 tile — exact cover by 256 threads
    const int cx = 2*(tid & 15), cy = 2*(tid >> 4);
    // conv2 patch: 2x2 at (py,px) in the 30x30 out tile — 225 of 256 threads
    const bool act2 = tid < 225;
    const int px = 2*(tid % 15), py = 2*(tid / 15);

    // validity of this thread's 2x2 c1 pixels (SAME padding: out-of-image c1 == 0)
    const int g1y = gy0 - 1 + cy, g1x = gx0 - 1 + cx;
    const bool vy0 = (unsigned)g1y < (unsigned)NP, vy1 = (unsigned)(g1y+1) < (unsigned)NP;
    const bool vx0 = (unsigned)g1x < (unsigned)NP, vx1 = (unsigned)(g1x+1) < (unsigned)NP;

    float acc2[8][2][2];
    #pragma unroll
    for (int o = 0; o < 8; ++o) {
        acc2[o][0][0]=0.f; acc2[o][0][1]=0.f; acc2[o][1][0]=0.f; acc2[o][1][1]=0.f;
    }

    #pragma unroll 1
    for (int ph = 0; ph < 4; ++ph) {
        const int oc0 = ph * 8;

        // ---- conv1: 8 oc into registers for this thread's 2x2 patch ----
        float acc1[8][2][2];
        #pragma unroll
        for (int o = 0; o < 8; ++o) {
            const float bv = b1[oc0 + o];
            acc1[o][0][0]=bv; acc1[o][0][1]=bv; acc1[o][1][0]=bv; acc1[o][1][1]=bv;
        }
        #pragma unroll 2
        for (int ic = 0; ic < 8; ++ic) {
            float win[4][4];
            #pragma unroll
            for (int r = 0; r < 4; ++r) {
                const float2 a = *(const float2*)&a_s[ic][cy+r][cx];
                const float2 c = *(const float2*)&a_s[ic][cy+r][cx+2];
                win[r][0]=a.x; win[r][1]=a.y; win[r][2]=c.x; win[r][3]=c.y;
            }
            #pragma unroll
            for (int o = 0; o < 8; ++o) {
                const float* w = w1 + ((size_t)(oc0+o)*8 + ic)*9;   // uniform -> s_load
                #pragma unroll
                for (int ky = 0; ky < 3; ++ky)
                    #pragma unroll
                    for (int kx = 0; kx < 3; ++kx) {
                        const float wv = w[ky*3+kx];
                        acc1[o][0][0] = fmaf(wv, win[ky  ][kx  ], acc1[o][0][0]);
                        acc1[o][0][1] = fmaf(wv, win[ky  ][kx+1], acc1[o][0][1]);
                        acc1[o][1][0] = fmaf(wv, win[ky+1][kx  ], acc1[o][1][0]);
                        acc1[o][1][1] = fmaf(wv, win[ky+1][kx+1], acc1[o][1][1]);
                    }
            }
        }

        __syncthreads();   // previous phase's conv2 reads of c1_s are done
        #pragma unroll
        for (int o = 0; o < 8; ++o) {
            const float v00 = (vy0 && vx0) ? fmaxf(acc1[o][0][0], 0.f) : 0.f;
            const float v01 = (vy0 && vx1) ? fmaxf(acc1[o][0][1], 0.f) : 0.f;
            const float v10 = (vy1 && vx0) ? fmaxf(acc1[o][1][0], 0.f) : 0.f;
            const float v11 = (vy1 && vx1) ? fmaxf(acc1[o][1][1], 0.f) : 0.f;
            *(float2*)&c1_s[o][cy  ][cx] = make_float2(v00, v01);
            *(float2*)&c1_s[o][cy+1][cx] = make_float2(v10, v11);
        }
        __syncthreads();   // c1_s visible

        // ---- conv2: accumulate these 8 ic into persistent acc2 ----
        if (act2) {
            #pragma unroll 2
            for (int icl = 0; icl < 8; ++icl) {
                float win[4][4];
                #pragma unroll
                for (int r = 0; r < 4; ++r) {
                    const float2 a = *(const float2*)&c1_s[icl][py+r][px];
                    const float2 c = *(const float2*)&c1_s[icl][py+r][px+2];
                    win[r][0]=a.x; win[r][1]=a.y; win[r][2]=c.x; win[r][3]=c.y;
                }
                #pragma unroll
                for (int o = 0; o < 8; ++o) {
                    const float* w = w2 + ((size_t)o*32 + oc0 + icl)*9;   // uniform -> s_load
                    #pragma unroll
                    for (int ky = 0; ky < 3; ++ky)
                        #pragma unroll
                        for (int kx = 0; kx < 3; ++kx) {
                            const float wv = w[ky*3+kx];
                            acc2[o][0][0] = fmaf(wv, win[ky  ][kx  ], acc2[o][0][0]);
                            acc2[o][0][1] = fmaf(wv, win[ky  ][kx+1], acc2[o][0][1]);
                            acc2[o][1][0] = fmaf(wv, win[ky+1][kx  ], acc2[o][1][0]);
                            acc2[o][1][1] = fmaf(wv, win[ky+1][kx+1], acc2[o][1][1]);
                        }
                }
            }
        }
    }

    // ---- epilogue: out[b, gy0+py+dy] += (1/8) * sum_o relu(acc2+b2) * value[b, gx0+px+dx] ----
    if (act2) {
        #pragma unroll
        for (int dy = 0; dy < 2; ++dy) {
            float s = 0.f;
            #pragma unroll
            for (int dx = 0; dx < 2; ++dx) {
                float cs = 0.f;
                #pragma unroll
                for (int o = 0; o < 8; ++o)
                    cs += fmaxf(acc2[o][dy][dx] + b2[o], 0.f);
                s = fmaf(cs, value[b*NP + gx0 + px + dx], s);
            }
            atomicAdd(&rsum[py + dy], s * 0.125f);
        }
    }
    __syncthreads();
    if (tid < 30) atomicAdd(out + (size_t)b*NP + gy0 + tid, rsum[tid]);
}

extern "C" void kernel_launch(void* const* d_in, const int* in_sizes, int n_in,
                              void* d_out, int out_size, void* d_ws, size_t ws_size,
                              hipStream_t stream)
{
    const float* query = (const float*)d_in[0];
    const float* key_t = (const float*)d_in[1];
    const float* value = (const float*)d_in[2];
    const float* Wq    = (const float*)d_in[3];
    const float* bq    = (const float*)d_in[4];
    const float* Wk    = (const float*)d_in[5];
    const float* bk    = (const float*)d_in[6];
    const float* c1w   = (const float*)d_in[7];
    const float* c1b   = (const float*)d_in[8];
    const float* c2w   = (const float*)d_in[9];
    const float* c2b   = (const float*)d_in[10];
    float* out = (float*)d_out;

    float* Q    = (float*)d_ws;
    float* K    = Q + (size_t)NBH*NP*NDK;      // +1,843,200 floats
    float* S    = K + (size_t)NBH*NP*NDK;      // +1,843,200 floats (S is 25,920,000 floats)
    int*   idxb = (int*)(S + (size_t)NBH*SSZ);
    float* pmax = (float*)(idxb + NBH*NP);
    int*   pidx = (int*)(pmax + 4*NBH*NP);

    hipMemsetAsync(d_out, 0, (size_t)out_size * sizeof(float), stream);

    proj_kernel<<<dim3(57, 8, 2), 256, 0, stream>>>(query, key_t, Wq, bq, Wk, bk, Q, K);
    scores_kernel<<<dim3(15, 15, 32), 256, 0, stream>>>(Q, K, S);
    argmax_part_kernel<<<dim3(4, 32, 4), 256, 0, stream>>>(S, pmax, pidx);
    argmax_combine_kernel<<<dim3(113), 256, 0, stream>>>(pmax, pidx, idxb);
    modulate_softmax_kernel<<<dim3(900, 32), 256, 0, stream>>>(S, idxb);
    conv_fused_kernel<<<dim3(30, 30, 4), 256, 0, stream>>>(S, c1w, c1b, c2w, c2b, value, out);
}

// Round 3
// 446.016 us; speedup vs baseline: 2.4442x; 1.6924x over previous
//
#include <hip/hip_runtime.h>

#define NB 4
#define NP 900
#define ND 512
#define NH 8
#define NDK 64
#define NROWS (NB*NP)          // 3600
#define SSZ (NP*NP)            // 810000
#define NBH (NB*NH)            // 32
#define SIDE 30

typedef unsigned short ushort_t;
typedef __attribute__((ext_vector_type(8)))  short  s8v;
typedef __attribute__((ext_vector_type(4)))  float  f4v;
typedef __attribute__((ext_vector_type(16))) float  f16v;

__device__ __forceinline__ ushort_t f2bf(float f) {
    unsigned int b = __float_as_uint(f);
    unsigned int r = (b + 0x7FFFu + ((b >> 16) & 1u)) >> 16;   // RNE, finite inputs
    return (ushort_t)r;
}

// ---------------- projection: O[b,h,p,c] = sum_k X[b,p,k] * W[h*64+c,k] + bias ----------
__global__ __launch_bounds__(256) void proj_kernel(
    const float* __restrict__ query, const float* __restrict__ key_t,
    const float* __restrict__ Wq, const float* __restrict__ bq,
    const float* __restrict__ Wk, const float* __restrict__ bk,
    float* __restrict__ Qo, float* __restrict__ Ko)
{
    const float *X, *W, *bias;
    float* O;
    if (blockIdx.z == 0) { X = query; W = Wq; bias = bq; O = Qo; }
    else                 { X = key_t; W = Wk; bias = bk; O = Ko; }

    __shared__ __align__(16) float As[16][68];
    __shared__ __align__(16) float Bs[16][68];

    const int i0 = blockIdx.x * 64;
    const int h  = blockIdx.y;
    const int j0 = h * 64;
    const int tid = threadIdx.x;
    const int tx = tid & 15, ty = tid >> 4;

    float acc[4][4] = {};

    for (int k0 = 0; k0 < ND; k0 += 16) {
        const int r  = tid >> 2;
        const int kk = (tid & 3) * 4;
        float4 av = make_float4(0.f, 0.f, 0.f, 0.f);
        const int gi = i0 + r;
        if (gi < NROWS) av = *(const float4*)(X + (size_t)gi * ND + k0 + kk);
        As[kk+0][r] = av.x; As[kk+1][r] = av.y; As[kk+2][r] = av.z; As[kk+3][r] = av.w;
        const float4 bv = *(const float4*)(W + (size_t)(j0 + r) * ND + k0 + kk);
        Bs[kk+0][r] = bv.x; Bs[kk+1][r] = bv.y; Bs[kk+2][r] = bv.z; Bs[kk+3][r] = bv.w;
        __syncthreads();
        #pragma unroll
        for (int k = 0; k < 16; ++k) {
            const float4 a4 = *(const float4*)&As[k][ty*4];
            const float4 b4 = *(const float4*)&Bs[k][tx*4];
            const float aa[4] = {a4.x, a4.y, a4.z, a4.w};
            const float bb[4] = {b4.x, b4.y, b4.z, b4.w};
            #pragma unroll
            for (int ii = 0; ii < 4; ++ii)
                #pragma unroll
                for (int jj = 0; jj < 4; ++jj)
                    acc[ii][jj] = fmaf(aa[ii], bb[jj], acc[ii][jj]);
        }
        __syncthreads();
    }

    #pragma unroll
    for (int ii = 0; ii < 4; ++ii) {
        const int gi = i0 + ty*4 + ii;
        if (gi >= NROWS) continue;
        const int b = gi / NP, p = gi - b * NP;
        float4 o;
        o.x = acc[ii][0] + bias[j0 + tx*4 + 0];
        o.y = acc[ii][1] + bias[j0 + tx*4 + 1];
        o.z = acc[ii][2] + bias[j0 + tx*4 + 2];
        o.w = acc[ii][3] + bias[j0 + tx*4 + 3];
        *(float4*)(O + ((size_t)(b*NH + h)*NP + p)*NDK + tx*4) = o;
    }
}

// ---------------- scores: S[bh,p,q] = sum_c Q[bh,p,c]*K[bh,q,c] ----------------
__global__ __launch_bounds__(256) void scores_kernel(
    const float* __restrict__ Q, const float* __restrict__ K, float* __restrict__ S)
{
    __shared__ __align__(16) float Qs[64][68];
    __shared__ __align__(16) float Ks[64][68];

    const int bh = blockIdx.z;
    const int q0 = blockIdx.x * 64;
    const int p0 = blockIdx.y * 64;
    const float* Qb = Q + (size_t)bh * NP * NDK;
    const float* Kb = K + (size_t)bh * NP * NDK;
    const int tid = threadIdx.x;
    const int tx = tid & 15, ty = tid >> 4;
    const int r = tid >> 2, l = tid & 3;

    #pragma unroll
    for (int u = 0; u < 4; ++u) {
        const int k = (l + 4*u) * 4;
        float4 qv = make_float4(0.f,0.f,0.f,0.f), kv = make_float4(0.f,0.f,0.f,0.f);
        if (p0 + r < NP) qv = *(const float4*)(Qb + (size_t)(p0 + r) * NDK + k);
        if (q0 + r < NP) kv = *(const float4*)(Kb + (size_t)(q0 + r) * NDK + k);
        Qs[k+0][r]=qv.x; Qs[k+1][r]=qv.y; Qs[k+2][r]=qv.z; Qs[k+3][r]=qv.w;
        Ks[k+0][r]=kv.x; Ks[k+1][r]=kv.y; Ks[k+2][r]=kv.z; Ks[k+3][r]=kv.w;
    }
    __syncthreads();

    float acc[4][4] = {};
    #pragma unroll 8
    for (int k = 0; k < NDK; ++k) {
        const float4 a4 = *(const float4*)&Qs[k][ty*4];
        const float4 b4 = *(const float4*)&Ks[k][tx*4];
        const float aa[4] = {a4.x, a4.y, a4.z, a4.w};
        const float bb[4] = {b4.x, b4.y, b4.z, b4.w};
        #pragma unroll
        for (int ii = 0; ii < 4; ++ii)
            #pragma unroll
            for (int jj = 0; jj < 4; ++jj)
                acc[ii][jj] = fmaf(aa[ii], bb[jj], acc[ii][jj]);
    }

    #pragma unroll
    for (int ii = 0; ii < 4; ++ii) {
        const int gp = p0 + ty*4 + ii;
        const int gq = q0 + tx*4;
        if (gp < NP && gq < NP) {
            float4 o;
            o.x = acc[ii][0]; o.y = acc[ii][1]; o.z = acc[ii][2]; o.w = acc[ii][3];
            *(float4*)(S + (size_t)bh*SSZ + (size_t)gp*NP + gq) = o;
        }
    }
}

// ---------------- column argmax over p (first-index tie-break) ----------
__global__ __launch_bounds__(256) void argmax_part_kernel(
    const float* __restrict__ S, float* __restrict__ pmax, int* __restrict__ pidx)
{
    const int bh = blockIdx.y;
    const int q = blockIdx.x * 256 + threadIdx.x;
    const int c = blockIdx.z;
    if (q >= NP) return;
    const float* col = S + (size_t)bh * SSZ + q;
    const int p0 = c * 225, p1 = p0 + 225;
    float best = -3.4e38f;
    int bi = p0;
    #pragma unroll 5
    for (int p = p0; p < p1; ++p) {
        const float v = col[(size_t)p * NP];
        if (v > best) { best = v; bi = p; }
    }
    pmax[((size_t)c*NBH + bh)*NP + q] = best;
    pidx[((size_t)c*NBH + bh)*NP + q] = bi;
}

__global__ __launch_bounds__(256) void argmax_combine_kernel(
    const float* __restrict__ pmax, const int* __restrict__ pidx, int* __restrict__ idxo)
{
    const int t = blockIdx.x * 256 + threadIdx.x;
    if (t >= NBH * NP) return;
    const int bh = t / NP, q = t - bh * NP;
    float best = -3.4e38f; int bi = 0;
    #pragma unroll
    for (int cc = 0; cc < 4; ++cc) {
        const float v = pmax[((size_t)cc*NBH + bh)*NP + q];
        const int  i = pidx[((size_t)cc*NBH + bh)*NP + q];
        if (v > best) { best = v; bi = i; }
    }
    idxo[t] = bi;
}

// ---------------- gaussian modulate + scale + softmax; writes bf16 channels-last S2 ----------
// S2[b][p][q][h]  (h contiguous: the conv kernel's MFMA A-fragment feed)
__global__ __launch_bounds__(256) void modulate_softmax_kernel(
    const float* __restrict__ S, const int* __restrict__ idx, ushort_t* __restrict__ S2)
{
    __shared__ int sidx[NH][NP];              // 28.8 KB
    __shared__ float vals[NP];
    __shared__ __align__(16) ushort_t ob[NP][NH];  // 14.4 KB
    __shared__ float red[4];

    const int p = blockIdx.x;
    const int b = blockIdx.y;
    const int tid = threadIdx.x;

    const float ax = -1.f + (2.f/29.f) * (float)(p % SIDE);
    const float ay = -1.f + (2.f/29.f) * (float)(p / SIDE);

    for (int i = tid; i < NH*NP; i += 256) {
        const int h = i / NP, q = i - h*NP;
        sidx[h][q] = idx[(b*NH + h)*NP + q];
    }
    __syncthreads();

    for (int h = 0; h < NH; ++h) {
        const float* row = S + (size_t)(b*NH + h)*SSZ + (size_t)p*NP;
        float lmax = -3.4e38f;
        for (int q = tid; q < NP; q += 256) {
            const int id = sidx[h][q];
            const float ix = (float)(id % SIDE);
            const float iy = (float)(id / SIDE);
            const float dx = ax - ix, dy = ay - iy;
            const float g = __expf(-(dx*dx + dy*dy) * 0.02f);
            const float v = row[q] * g * 0.125f;
            vals[q] = v;
            lmax = fmaxf(lmax, v);
        }
        #pragma unroll
        for (int off = 32; off > 0; off >>= 1)
            lmax = fmaxf(lmax, __shfl_down(lmax, off, 64));
        if ((tid & 63) == 0) red[tid >> 6] = lmax;
        __syncthreads();
        const float rmax = fmaxf(fmaxf(red[0], red[1]), fmaxf(red[2], red[3]));

        float lsum = 0.f;
        for (int q = tid; q < NP; q += 256) {
            const float e = __expf(vals[q] - rmax);
            vals[q] = e;
            lsum += e;
        }
        #pragma unroll
        for (int off = 32; off > 0; off >>= 1)
            lsum += __shfl_down(lsum, off, 64);
        __syncthreads();
        if ((tid & 63) == 0) red[tid >> 6] = lsum;
        __syncthreads();
        const float inv = 1.f / (red[0] + red[1] + red[2] + red[3]);
        for (int q = tid; q < NP; q += 256) ob[q][h] = f2bf(vals[q] * inv);
        __syncthreads();   // red[] reused next h; vals done
    }

    for (int q = tid; q < NP; q += 256)
        *(uint4*)(S2 + (((size_t)b*NP + p)*NP + q)*NH) = *(const uint4*)&ob[q][0];
}

// ---------------- weight fragment prep (B-operand layouts, bf16) ----------------
// w1b[c in 0..4][lane 0..63][j 0..7]: B[k][n] for mfma_32x32x16: n=lane&31, k=(lane>>5)*8+j
//   chunk c covers taps (2c, 2c+1); chunk 4 = tap 8 in half 0, zeros in half 1.
// w2b[t in 0..8][lane 0..63][j 0..7]: B[k][n] for mfma_16x16x32: n=lane&15, k=(lane>>4)*8+j
//   n>=8 lanes zeroed (conv2 has only 8 output channels).
__global__ void prep_weights_kernel(
    const float* __restrict__ c1w, const float* __restrict__ c2w,
    ushort_t* __restrict__ w1b, ushort_t* __restrict__ w2b)
{
    const int tid = threadIdx.x;
    for (int i = tid; i < 5*64; i += 256) {
        const int c = i >> 6, l = i & 63;
        const int oc = l & 31, hf = l >> 5;
        #pragma unroll
        for (int j = 0; j < 8; ++j) {
            float wv;
            if (c < 4)      wv = c1w[(oc*8 + j)*9 + (2*c + hf)];
            else            wv = hf ? 0.f : c1w[(oc*8 + j)*9 + 8];
            w1b[(i)*8 + j] = f2bf(wv);
        }
    }
    for (int i = tid; i < 9*64; i += 256) {
        const int t = i >> 6, l = i & 63;
        const int n = l & 15, qd = l >> 4;
        #pragma unroll
        for (int j = 0; j < 8; ++j) {
            const int k = qd*8 + j;
            const float wv = (n < 8) ? c2w[(n*32 + k)*9 + t] : 0.f;
            w2b[(i)*8 + j] = f2bf(wv);
        }
    }
}

// ---------------- MFMA fused conv1+conv2+value-reduce ----------------
// Per-wave-independent 30(x) x 9(y) output stripe; block = 4 waves = 36 rows; grid (30,25,4).
// conv1: mfma_32x32x16_bf16, M=32 (c1 row), N=32 (oc), K=16 (2 taps x 8 ic). 5 MFMA/row.
// c1 ring: 4 rows x 34 x 32oc bf16 per wave (LDS round-trip for D->A layout transform).
// conv2: mfma_16x16x32_bf16, M=16 (q), N=16 (8 oc used), K=32 (oc) per tap. 18 MFMA/row.
__global__ __launch_bounds__(256) void conv_mfma_kernel(
    const ushort_t* __restrict__ S2, const ushort_t* __restrict__ w1b,
    const ushort_t* __restrict__ w2b,
    const float* __restrict__ b1, const float* __restrict__ b2,
    const float* __restrict__ value, float* __restrict__ out)
{
    __shared__ __align__(16) ushort_t a_s[4][13][34][8];    // 28,288 B: attn tile, bf16 ch-last
    __shared__ __align__(16) ushort_t c1r[4][4][34][32];    // 34,816 B: c1 ring (x 32..33 = guard)

    const int tid  = threadIdx.x;
    const int lane = tid & 63;
    const int w    = tid >> 6;
    const int b    = blockIdx.z;
    const int gx0  = blockIdx.x * 30;
    const int gy0w = blockIdx.y * 36 + w * 9;

    // ---- stage attn tile (zeros outside image) ----
    for (int i = lane; i < 13*34; i += 64) {
        const int ai = i / 34, xi = i - ai*34;
        const int gp = gy0w - 2 + ai, gq = gx0 - 2 + xi;
        uint4 v = make_uint4(0u,0u,0u,0u);
        if ((unsigned)gp < (unsigned)NP && (unsigned)gq < (unsigned)NP)
            v = *(const uint4*)(S2 + (((size_t)b*NP + gp)*NP + gq)*NH);
        *(uint4*)&a_s[w][ai][xi][0] = v;
    }

    // ---- weight fragments (global, L1/L2 cached) ----
    s8v w1f[5], w2f[9];
    #pragma unroll
    for (int c = 0; c < 5; ++c) w1f[c] = *(const s8v*)(w1b + ((size_t)c*64 + lane)*8);
    #pragma unroll
    for (int t = 0; t < 9; ++t) w2f[t] = *(const s8v*)(w2b + ((size_t)t*64 + lane)*8);

    const float b1v = b1[lane & 31];
    const float b2v = ((lane & 15) < 8) ? b2[lane & 15] : 0.f;

    const int m    = lane & 31;    // conv1 A-frag M index (c1 x)
    const int half = lane >> 5;    // conv1 K-half (tap-in-pair)
    const int m16  = lane & 15;    // conv2 A-frag M index
    const int qd   = lane >> 4;    // conv2 K-quad

    // value segment for this lane's conv2 D positions
    float vseg[2][4];
    #pragma unroll
    for (int g = 0; g < 2; ++g)
        #pragma unroll
        for (int r = 0; r < 4; ++r) {
            const int ql = g*16 + qd*4 + r;
            vseg[g][r] = (ql < 30) ? value[b*NP + gx0 + ql] : 0.f;
        }

    __syncthreads();   // a_s ready (cheap one-time barrier; main loop barrier-free)

    // ---- conv1: produce c1 row yc into ring slot yc&3 ----
    auto conv1_row = [&](int yc) {
        const bool rowok = (unsigned)(gy0w - 1 + yc) < (unsigned)NP;
        const s8v A0 = *(const s8v*)&a_s[w][yc       ][m + half          ][0];  // taps 0,1
        const s8v A1 = *(const s8v*)&a_s[w][yc + half][half ? m : (m + 2)][0];  // taps 2,3
        const s8v A2 = *(const s8v*)&a_s[w][yc + 1   ][m + 1 + half      ][0];  // taps 4,5
        const s8v A3 = *(const s8v*)&a_s[w][yc + 2   ][m + half          ][0];  // taps 6,7
        const s8v A4 = *(const s8v*)&a_s[w][yc + 2   ][m + 2             ][0];  // tap 8 (+zero)
        f16v acc = {};
        acc = __builtin_amdgcn_mfma_f32_32x32x16_bf16(A0, w1f[0], acc, 0, 0, 0);
        acc = __builtin_amdgcn_mfma_f32_32x32x16_bf16(A1, w1f[1], acc, 0, 0, 0);
        acc = __builtin_amdgcn_mfma_f32_32x32x16_bf16(A2, w1f[2], acc, 0, 0, 0);
        acc = __builtin_amdgcn_mfma_f32_32x32x16_bf16(A3, w1f[3], acc, 0, 0, 0);
        acc = __builtin_amdgcn_mfma_f32_32x32x16_bf16(A4, w1f[4], acc, 0, 0, 0);
        const int slot = yc & 3;
        #pragma unroll
        for (int r = 0; r < 16; ++r) {
            const int x_l = (r & 3) + 8*(r >> 2) + 4*half;   // D row = c1 x
            float f = fmaxf(acc[r] + b1v, 0.f);
            const bool ok = rowok && ((unsigned)(gx0 - 1 + x_l) < (unsigned)NP);
            f = ok ? f : 0.f;                                // SAME-pad: OOB c1 = 0
            c1r[w][slot][x_l][lane & 31] = f2bf(f);
        }
    };

    // ---- conv2: out row yo from ring rows yo..yo+2 ----
    auto conv2_row = [&](int yo) {
        f4v acc0 = {0.f,0.f,0.f,0.f}, acc1 = {0.f,0.f,0.f,0.f};
        #pragma unroll
        for (int dy = 0; dy < 3; ++dy) {
            const int slot = (yo + dy) & 3;
            #pragma unroll
            for (int dx = 0; dx < 3; ++dx) {
                const s8v a0 = *(const s8v*)&c1r[w][slot][     m16 + dx][qd*8];
                const s8v a1 = *(const s8v*)&c1r[w][slot][16 + m16 + dx][qd*8];
                acc0 = __builtin_amdgcn_mfma_f32_16x16x32_bf16(a0, w2f[dy*3+dx], acc0, 0, 0, 0);
                acc1 = __builtin_amdgcn_mfma_f32_16x16x32_bf16(a1, w2f[dy*3+dx], acc1, 0, 0, 0);
            }
        }
        float s = 0.f;
        const bool ocok = (lane & 15) < 8;
        #pragma unroll
        for (int r = 0; r < 4; ++r) {
            const float f0 = fmaxf(acc0[r] + b2v, 0.f);
            const float f1 = fmaxf(acc1[r] + b2v, 0.f);
            s += ocok ? f0 * vseg[0][r] : 0.f;
            s += ocok ? f1 * vseg[1][r] : 0.f;   // vseg already 0 for q>=30
        }
        #pragma unroll
        for (int off = 32; off > 0; off >>= 1)
            s += __shfl_down(s, off, 64);
        if (lane == 0)
            atomicAdd(out + (size_t)b*NP + (gy0w + yo), s * 0.125f);
    };

    conv1_row(0);
    conv1_row(1);
    conv1_row(2);
    #pragma unroll 1
    for (int yo = 0; yo < 9; ++yo) {
        if (yo < 8) conv1_row(yo + 3);   // slot (yo+3)&3 disjoint from reads yo..yo+2
        conv2_row(yo);
    }
}

extern "C" void kernel_launch(void* const* d_in, const int* in_sizes, int n_in,
                              void* d_out, int out_size, void* d_ws, size_t ws_size,
                              hipStream_t stream)
{
    const float* query = (const float*)d_in[0];
    const float* key_t = (const float*)d_in[1];
    const float* value = (const float*)d_in[2];
    const float* Wq    = (const float*)d_in[3];
    const float* bq    = (const float*)d_in[4];
    const float* Wk    = (const float*)d_in[5];
    const float* bk    = (const float*)d_in[6];
    const float* c1w   = (const float*)d_in[7];
    const float* c1b   = (const float*)d_in[8];
    const float* c2w   = (const float*)d_in[9];
    const float* c2b   = (const float*)d_in[10];
    float* out = (float*)d_out;

    float*    Q    = (float*)d_ws;
    float*    K    = Q + (size_t)NBH*NP*NDK;
    float*    S    = K + (size_t)NBH*NP*NDK;
    int*      idxb = (int*)(S + (size_t)NBH*SSZ);
    float*    pmax = (float*)(idxb + NBH*NP);
    int*      pidx = (int*)(pmax + 4*NBH*NP);
    ushort_t* S2   = (ushort_t*)(pidx + 4*NBH*NP);          // 4*900*900*8 bf16 = 51.84 MB
    ushort_t* w1b  = S2 + (size_t)NB*NP*NP*NH;
    ushort_t* w2b  = w1b + 5*64*8;

    hipMemsetAsync(d_out, 0, (size_t)out_size * sizeof(float), stream);

    prep_weights_kernel<<<dim3(1), 256, 0, stream>>>(c1w, c2w, w1b, w2b);
    proj_kernel<<<dim3(57, 8, 2), 256, 0, stream>>>(query, key_t, Wq, bq, Wk, bk, Q, K);
    scores_kernel<<<dim3(15, 15, 32), 256, 0, stream>>>(Q, K, S);
    argmax_part_kernel<<<dim3(4, 32, 4), 256, 0, stream>>>(S, pmax, pidx);
    argmax_combine_kernel<<<dim3(113), 256, 0, stream>>>(pmax, pidx, idxb);
    modulate_softmax_kernel<<<dim3(900, 4), 256, 0, stream>>>(S, idxb, S2);
    conv_mfma_kernel<<<dim3(30, 25, 4), 256, 0, stream>>>(S2, w1b, w2b, c1b, c2b, value, out);
}

// Round 4
// 310.433 us; speedup vs baseline: 3.5117x; 1.4368x over previous
//
#include <hip/hip_runtime.h>

#define NB 4
#define NP 900
#define ND 512
#define NH 8
#define NDK 64
#define NROWS (NB*NP)          // 3600
#define SSZ (NP*NP)            // 810000
#define NBH (NB*NH)            // 32
#define SIDE 30

typedef unsigned short ushort_t;
typedef unsigned long long u64_t;
typedef __attribute__((ext_vector_type(8)))  short  s8v;
typedef __attribute__((ext_vector_type(4)))  float  f4v;
typedef __attribute__((ext_vector_type(16))) float  f16v;

__device__ __forceinline__ ushort_t f2bf(float f) {
    unsigned int b = __float_as_uint(f);
    unsigned int r = (b + 0x7FFFu + ((b >> 16) & 1u)) >> 16;   // RNE, finite inputs
    return (ushort_t)r;
}
// order-preserving f32 -> u32 (total order; equal floats -> equal codes)
__device__ __forceinline__ unsigned int fenc(float v) {
    unsigned int b = __float_as_uint(v);
    return (b & 0x80000000u) ? ~b : (b | 0x80000000u);
}

// ---------------- projection: O[b,h,p,c] = sum_k X[b,p,k] * W[h*64+c,k] + bias ----------
__global__ __launch_bounds__(256) void proj_kernel(
    const float* __restrict__ query, const float* __restrict__ key_t,
    const float* __restrict__ Wq, const float* __restrict__ bq,
    const float* __restrict__ Wk, const float* __restrict__ bk,
    float* __restrict__ Qo, float* __restrict__ Ko)
{
    const float *X, *W, *bias;
    float* O;
    if (blockIdx.z == 0) { X = query; W = Wq; bias = bq; O = Qo; }
    else                 { X = key_t; W = Wk; bias = bk; O = Ko; }

    __shared__ __align__(16) float As[16][68];
    __shared__ __align__(16) float Bs[16][68];

    const int i0 = blockIdx.x * 64;
    const int h  = blockIdx.y;
    const int j0 = h * 64;
    const int tid = threadIdx.x;
    const int tx = tid & 15, ty = tid >> 4;

    float acc[4][4] = {};

    for (int k0 = 0; k0 < ND; k0 += 16) {
        const int r  = tid >> 2;
        const int kk = (tid & 3) * 4;
        float4 av = make_float4(0.f, 0.f, 0.f, 0.f);
        const int gi = i0 + r;
        if (gi < NROWS) av = *(const float4*)(X + (size_t)gi * ND + k0 + kk);
        As[kk+0][r] = av.x; As[kk+1][r] = av.y; As[kk+2][r] = av.z; As[kk+3][r] = av.w;
        const float4 bv = *(const float4*)(W + (size_t)(j0 + r) * ND + k0 + kk);
        Bs[kk+0][r] = bv.x; Bs[kk+1][r] = bv.y; Bs[kk+2][r] = bv.z; Bs[kk+3][r] = bv.w;
        __syncthreads();
        #pragma unroll
        for (int k = 0; k < 16; ++k) {
            const float4 a4 = *(const float4*)&As[k][ty*4];
            const float4 b4 = *(const float4*)&Bs[k][tx*4];
            const float aa[4] = {a4.x, a4.y, a4.z, a4.w};
            const float bb[4] = {b4.x, b4.y, b4.z, b4.w};
            #pragma unroll
            for (int ii = 0; ii < 4; ++ii)
                #pragma unroll
                for (int jj = 0; jj < 4; ++jj)
                    acc[ii][jj] = fmaf(aa[ii], bb[jj], acc[ii][jj]);
        }
        __syncthreads();
    }

    #pragma unroll
    for (int ii = 0; ii < 4; ++ii) {
        const int gi = i0 + ty*4 + ii;
        if (gi >= NROWS) continue;
        const int b = gi / NP, p = gi - b * NP;
        float4 o;
        o.x = acc[ii][0] + bias[j0 + tx*4 + 0];
        o.y = acc[ii][1] + bias[j0 + tx*4 + 1];
        o.z = acc[ii][2] + bias[j0 + tx*4 + 2];
        o.w = acc[ii][3] + bias[j0 + tx*4 + 3];
        *(float4*)(O + ((size_t)(b*NH + h)*NP + p)*NDK + tx*4) = o;
    }
}

// ---------------- scores + fused column argmax ----------------
// S[bh,p,q] = sum_c Q[bh,p,c]*K[bh,q,c]; amax[bh][q] = packed max-(value,first-p) key
__global__ __launch_bounds__(256) void scores_kernel(
    const float* __restrict__ Q, const float* __restrict__ K, float* __restrict__ S,
    u64_t* __restrict__ amax)
{
    __shared__ __align__(16) float Qs[64][68];
    __shared__ __align__(16) float Ks[64][68];
    __shared__ u64_t amax_s[64];

    const int bh = blockIdx.z;
    const int q0 = blockIdx.x * 64;
    const int p0 = blockIdx.y * 64;
    const float* Qb = Q + (size_t)bh * NP * NDK;
    const float* Kb = K + (size_t)bh * NP * NDK;
    const int tid = threadIdx.x;
    const int tx = tid & 15, ty = tid >> 4;
    const int r = tid >> 2, l = tid & 3;

    if (tid < 64) amax_s[tid] = 0ull;

    #pragma unroll
    for (int u = 0; u < 4; ++u) {
        const int k = (l + 4*u) * 4;
        float4 qv = make_float4(0.f,0.f,0.f,0.f), kv = make_float4(0.f,0.f,0.f,0.f);
        if (p0 + r < NP) qv = *(const float4*)(Qb + (size_t)(p0 + r) * NDK + k);
        if (q0 + r < NP) kv = *(const float4*)(Kb + (size_t)(q0 + r) * NDK + k);
        Qs[k+0][r]=qv.x; Qs[k+1][r]=qv.y; Qs[k+2][r]=qv.z; Qs[k+3][r]=qv.w;
        Ks[k+0][r]=kv.x; Ks[k+1][r]=kv.y; Ks[k+2][r]=kv.z; Ks[k+3][r]=kv.w;
    }
    __syncthreads();

    float acc[4][4] = {};
    #pragma unroll 8
    for (int k = 0; k < NDK; ++k) {
        const float4 a4 = *(const float4*)&Qs[k][ty*4];
        const float4 b4 = *(const float4*)&Ks[k][tx*4];
        const float aa[4] = {a4.x, a4.y, a4.z, a4.w};
        const float bb[4] = {b4.x, b4.y, b4.z, b4.w};
        #pragma unroll
        for (int ii = 0; ii < 4; ++ii)
            #pragma unroll
            for (int jj = 0; jj < 4; ++jj)
                acc[ii][jj] = fmaf(aa[ii], bb[jj], acc[ii][jj]);
    }

    #pragma unroll
    for (int ii = 0; ii < 4; ++ii) {
        const int gp = p0 + ty*4 + ii;
        const int gq = q0 + tx*4;
        if (gp < NP && gq < NP) {
            float4 o;
            o.x = acc[ii][0]; o.y = acc[ii][1]; o.z = acc[ii][2]; o.w = acc[ii][3];
            *(float4*)(S + (size_t)bh*SSZ + (size_t)gp*NP + gq) = o;
        }
    }

    // fused argmax over p: key = (enc(v)<<32) | (899-p)  -> max = (max v, first p)
    #pragma unroll
    for (int jj = 0; jj < 4; ++jj) {
        const int gq = q0 + tx*4 + jj;
        if (gq >= NP) continue;
        u64_t key = 0ull;
        #pragma unroll
        for (int ii = 0; ii < 4; ++ii) {
            const int gp = p0 + ty*4 + ii;
            if (gp >= NP) continue;
            const u64_t k = ((u64_t)fenc(acc[ii][jj]) << 32) | (unsigned)(899 - gp);
            key = key > k ? key : k;
        }
        atomicMax(&amax_s[tx*4 + jj], key);
    }
    __syncthreads();
    if (tid < 64 && q0 + tid < NP)
        atomicMax(&amax[(size_t)bh*NP + q0 + tid], amax_s[tid]);
}

// ---------------- decode packed argmax -> (ix, iy) floats (reference quirk: raw ints) ----------
__global__ __launch_bounds__(256) void decode_kernel(
    const u64_t* __restrict__ amax, float2* __restrict__ gpos)
{
    const int t = blockIdx.x * 256 + threadIdx.x;
    if (t >= NBH * NP) return;
    const int idx = 899 - (int)(unsigned)(amax[t] & 0xFFFFFFFFull);
    gpos[t] = make_float2((float)(idx % SIDE), (float)(idx / SIDE));
}

// ---------------- gaussian modulate + scale + softmax; writes bf16 channels-last S2 ----------
// Wave w handles heads {w, w+4}; row fully register-resident; 1 block barrier total.
__global__ __launch_bounds__(256) void modulate_softmax_kernel(
    const float* __restrict__ S, const float2* __restrict__ gpos, ushort_t* __restrict__ S2)
{
    __shared__ __align__(16) ushort_t ob[NP][NH];  // 14.4 KB

    const int p = blockIdx.x;
    const int b = blockIdx.y;
    const int tid = threadIdx.x;
    const int lane = tid & 63;
    const int w = tid >> 6;

    const float ax = -1.f + (2.f/29.f) * (float)(p % SIDE);
    const float ay = -1.f + (2.f/29.f) * (float)(p / SIDE);

    #pragma unroll 1
    for (int hh = 0; hh < 2; ++hh) {
        const int h = w + hh*4;
        const float* row = S + (size_t)(b*NH + h)*SSZ + (size_t)p*NP;
        const float2* gp = gpos + (b*NH + h)*NP;

        float rv[15];
        float lmax = -3.4e38f;
        #pragma unroll
        for (int i = 0; i < 15; ++i) {
            const int q = lane + 64*i;
            float v = -3.4e38f;
            if (q < NP) {
                const float2 g2 = gp[q];
                const float dx = ax - g2.x, dy = ay - g2.y;
                const float g = __expf(-(dx*dx + dy*dy) * 0.02f);  // 1/(2*sigma^2)
                v = row[q] * g * 0.125f;                            // /sqrt(dk)
            }
            rv[i] = v;
            lmax = fmaxf(lmax, v);
        }
        #pragma unroll
        for (int off = 32; off > 0; off >>= 1)
            lmax = fmaxf(lmax, __shfl_xor(lmax, off, 64));

        float lsum = 0.f;
        #pragma unroll
        for (int i = 0; i < 15; ++i) {
            const int q = lane + 64*i;
            const float e = (q < NP) ? __expf(rv[i] - lmax) : 0.f;
            rv[i] = e;
            lsum += e;
        }
        #pragma unroll
        for (int off = 32; off > 0; off >>= 1)
            lsum += __shfl_xor(lsum, off, 64);
        const float inv = 1.f / lsum;

        #pragma unroll
        for (int i = 0; i < 15; ++i) {
            const int q = lane + 64*i;
            if (q < NP) ob[q][h] = f2bf(rv[i] * inv);
        }
    }
    __syncthreads();
    for (int q = tid; q < NP; q += 256)
        *(uint4*)(S2 + (((size_t)b*NP + p)*NP + q)*NH) = *(const uint4*)&ob[q][0];
}

// ---------------- weight fragment prep (B-operand layouts, bf16) ----------------
__global__ void prep_weights_kernel(
    const float* __restrict__ c1w, const float* __restrict__ c2w,
    ushort_t* __restrict__ w1b, ushort_t* __restrict__ w2b)
{
    const int tid = threadIdx.x;
    for (int i = tid; i < 5*64; i += 256) {
        const int c = i >> 6, l = i & 63;
        const int oc = l & 31, hf = l >> 5;
        #pragma unroll
        for (int j = 0; j < 8; ++j) {
            float wv;
            if (c < 4)      wv = c1w[(oc*8 + j)*9 + (2*c + hf)];
            else            wv = hf ? 0.f : c1w[(oc*8 + j)*9 + 8];
            w1b[(i)*8 + j] = f2bf(wv);
        }
    }
    for (int i = tid; i < 9*64; i += 256) {
        const int t = i >> 6, l = i & 63;
        const int n = l & 15, qd = l >> 4;
        #pragma unroll
        for (int j = 0; j < 8; ++j) {
            const int k = qd*8 + j;
            const float wv = (n < 8) ? c2w[(n*32 + k)*9 + t] : 0.f;
            w2b[(i)*8 + j] = f2bf(wv);
        }
    }
}

// ---------------- MFMA fused conv1+conv2+value-reduce ----------------
// Per-wave 30(x) x 9(y) stripe. For each of 11 c1 rows: conv1 (5 MFMA) -> single-row LDS
// buffer -> read 6 fragments ONCE -> scatter into 3 rolling conv2 output accumulators.
// 66 ds_read_b128/stripe (was 162); barrier-free; LDS ~36 KB -> 4 blocks/CU.
__global__ __launch_bounds__(256, 4) void conv_mfma_kernel(
    const ushort_t* __restrict__ S2, const ushort_t* __restrict__ w1b,
    const ushort_t* __restrict__ w2b,
    const float* __restrict__ b1, const float* __restrict__ b2,
    const float* __restrict__ value, float* __restrict__ out)
{
    __shared__ __align__(16) ushort_t a_s[4][13][34][8];    // 28,288 B: attn tile, bf16 ch-last
    __shared__ __align__(16) ushort_t c1row[4][34][32];     //  8,704 B: one c1 row per wave

    const int tid  = threadIdx.x;
    const int lane = tid & 63;
    const int w    = tid >> 6;
    const int b    = blockIdx.z;
    const int gx0  = blockIdx.x * 30;
    const int gy0w = blockIdx.y * 36 + w * 9;

    // zero guard columns x=32,33 (read by group-1 fragments at m16=15,dx=2; results discarded
    // via vseg=0 but must be finite)
    c1row[w][32 + (lane >> 5)][lane & 31] = 0;

    // ---- stage attn tile (zeros outside image); per-wave, no barrier needed ----
    for (int i = lane; i < 13*34; i += 64) {
        const int ai = i / 34, xi = i - ai*34;
        const int gp = gy0w - 2 + ai, gq = gx0 - 2 + xi;
        uint4 v = make_uint4(0u,0u,0u,0u);
        if ((unsigned)gp < (unsigned)NP && (unsigned)gq < (unsigned)NP)
            v = *(const uint4*)(S2 + (((size_t)b*NP + gp)*NP + gq)*NH);
        *(uint4*)&a_s[w][ai][xi][0] = v;
    }

    // ---- weight fragments (global, L2-cached) ----
    s8v w1f[5], w2f[9];
    #pragma unroll
    for (int c = 0; c < 5; ++c) w1f[c] = *(const s8v*)(w1b + ((size_t)c*64 + lane)*8);
    #pragma unroll
    for (int t = 0; t < 9; ++t) w2f[t] = *(const s8v*)(w2b + ((size_t)t*64 + lane)*8);

    const float b1v = b1[lane & 31];
    const float b2v = ((lane & 15) < 8) ? b2[lane & 15] : 0.f;

    const int m    = lane & 31;    // conv1 A-frag M index (c1 x)
    const int half = lane >> 5;    // conv1 K-half (tap-in-pair)
    const int m16  = lane & 15;    // conv2 A-frag M index
    const int qd   = lane >> 4;    // conv2 K-quad

    float vseg[2][4];
    #pragma unroll
    for (int g = 0; g < 2; ++g)
        #pragma unroll
        for (int r = 0; r < 4; ++r) {
            const int ql = g*16 + qd*4 + r;
            vseg[g][r] = (ql < 30) ? value[b*NP + gx0 + ql] : 0.f;
        }

    f4v o0[3] = {}, o1[3] = {};   // rolling accumulators, out row yo -> slot yo%3

    #pragma unroll
    for (int yc = 0; yc < 11; ++yc) {
        // ---- conv1: c1 row yc (image row gy0w-1+yc) -> c1row[w] ----
        {
            const bool rowok = (unsigned)(gy0w - 1 + yc) < (unsigned)NP;
            const s8v A0 = *(const s8v*)&a_s[w][yc       ][m + half          ][0];  // taps 0,1
            const s8v A1 = *(const s8v*)&a_s[w][yc + half][half ? m : (m + 2)][0];  // taps 2,3
            const s8v A2 = *(const s8v*)&a_s[w][yc + 1   ][m + 1 + half      ][0];  // taps 4,5
            const s8v A3 = *(const s8v*)&a_s[w][yc + 2   ][m + half          ][0];  // taps 6,7
            const s8v A4 = *(const s8v*)&a_s[w][yc + 2   ][m + 2             ][0];  // tap 8
            f16v acc = {};
            acc = __builtin_amdgcn_mfma_f32_32x32x16_bf16(A0, w1f[0], acc, 0, 0, 0);
            acc = __builtin_amdgcn_mfma_f32_32x32x16_bf16(A1, w1f[1], acc, 0, 0, 0);
            acc = __builtin_amdgcn_mfma_f32_32x32x16_bf16(A2, w1f[2], acc, 0, 0, 0);
            acc = __builtin_amdgcn_mfma_f32_32x32x16_bf16(A3, w1f[3], acc, 0, 0, 0);
            acc = __builtin_amdgcn_mfma_f32_32x32x16_bf16(A4, w1f[4], acc, 0, 0, 0);
            #pragma unroll
            for (int r = 0; r < 16; ++r) {
                const int x_l = (r & 3) + 8*(r >> 2) + 4*half;   // D row = c1 x
                float f = fmaxf(acc[r] + b1v, 0.f);
                const bool ok = rowok && ((unsigned)(gx0 - 1 + x_l) < (unsigned)NP);
                f = ok ? f : 0.f;                                // SAME-pad: OOB c1 = 0
                c1row[w][x_l][lane & 31] = f2bf(f);
            }
        }
        // same-wave LDS write->read: DS ops execute in order per wave; drain counter
        asm volatile("s_waitcnt lgkmcnt(0)" ::: "memory");

        // ---- conv2: read 6 fragments once, scatter into out rows yc-2..yc ----
        #pragma unroll
        for (int dx = 0; dx < 3; ++dx) {
            const s8v a0 = *(const s8v*)&c1row[w][     m16 + dx][qd*8];
            const s8v a1 = *(const s8v*)&c1row[w][16 + m16 + dx][qd*8];
            #pragma unroll
            for (int dy = 0; dy < 3; ++dy) {
                const int yo = yc - dy;
                if (yo < 0 || yo > 8) continue;
                const int sl = yo % 3;
                o0[sl] = __builtin_amdgcn_mfma_f32_16x16x32_bf16(a0, w2f[dy*3+dx], o0[sl], 0, 0, 0);
                o1[sl] = __builtin_amdgcn_mfma_f32_16x16x32_bf16(a1, w2f[dy*3+dx], o1[sl], 0, 0, 0);
            }
        }

        // ---- out row yc-2 complete: epilogue + reset slot ----
        if (yc >= 2) {
            const int yo = yc - 2;
            const int sl = yo % 3;
            float s = 0.f;
            const bool ocok = (lane & 15) < 8;
            #pragma unroll
            for (int r = 0; r < 4; ++r) {
                const float f0 = fmaxf(o0[sl][r] + b2v, 0.f);
                const float f1 = fmaxf(o1[sl][r] + b2v, 0.f);
                s += ocok ? f0 * vseg[0][r] : 0.f;
                s += ocok ? f1 * vseg[1][r] : 0.f;
            }
            #pragma unroll
            for (int off = 32; off > 0; off >>= 1)
                s += __shfl_down(s, off, 64);
            if (lane == 0)
                atomicAdd(out + (size_t)b*NP + (gy0w + yo), s * 0.125f);
            o0[sl] = (f4v){0.f,0.f,0.f,0.f};
            o1[sl] = (f4v){0.f,0.f,0.f,0.f};
        }
    }
}

extern "C" void kernel_launch(void* const* d_in, const int* in_sizes, int n_in,
                              void* d_out, int out_size, void* d_ws, size_t ws_size,
                              hipStream_t stream)
{
    const float* query = (const float*)d_in[0];
    const float* key_t = (const float*)d_in[1];
    const float* value = (const float*)d_in[2];
    const float* Wq    = (const float*)d_in[3];
    const float* bq    = (const float*)d_in[4];
    const float* Wk    = (const float*)d_in[5];
    const float* bk    = (const float*)d_in[6];
    const float* c1w   = (const float*)d_in[7];
    const float* c1b   = (const float*)d_in[8];
    const float* c2w   = (const float*)d_in[9];
    const float* c2b   = (const float*)d_in[10];
    float* out = (float*)d_out;

    float*    Q    = (float*)d_ws;
    float*    K    = Q + (size_t)NBH*NP*NDK;
    float*    S    = K + (size_t)NBH*NP*NDK;
    u64_t*    amax = (u64_t*)(S + (size_t)NBH*SSZ);         // 32*900*8 B, 8-aligned
    float2*   gpos = (float2*)(amax + (size_t)NBH*NP);
    ushort_t* S2   = (ushort_t*)(gpos + (size_t)NBH*NP);    // 4*900*900*8 bf16 = 51.84 MB
    ushort_t* w1b  = S2 + (size_t)NB*NP*NP*NH;
    ushort_t* w2b  = w1b + 5*64*8;

    hipMemsetAsync(d_out, 0, (size_t)out_size * sizeof(float), stream);
    hipMemsetAsync(amax, 0, (size_t)NBH*NP*sizeof(u64_t), stream);

    prep_weights_kernel<<<dim3(1), 256, 0, stream>>>(c1w, c2w, w1b, w2b);
    proj_kernel<<<dim3(57, 8, 2), 256, 0, stream>>>(query, key_t, Wq, bq, Wk, bk, Q, K);
    scores_kernel<<<dim3(15, 15, 32), 256, 0, stream>>>(Q, K, S, amax);
    decode_kernel<<<dim3(113), 256, 0, stream>>>(amax, gpos);
    modulate_softmax_kernel<<<dim3(900, 4), 256, 0, stream>>>(S, gpos, S2);
    conv_mfma_kernel<<<dim3(30, 25, 4), 256, 0, stream>>>(S2, w1b, w2b, c1b, c2b, value, out);
}